// Round 7
// baseline (172.640 us; speedup 1.0000x reference)
//
#include <hip/hip_runtime.h>
#include <hip/hip_bf16.h>
#include <hip/hip_cooperative_groups.h>
#include <cmath>

namespace cg = cooperative_groups;

#define Bb 4
#define Ll 2048
#define Dd 1024
#define Hh 64

typedef float f32x4 __attribute__((ext_vector_type(4)));
typedef short s16x8 __attribute__((ext_vector_type(8)));

#if __has_builtin(__builtin_amdgcn_exp2f)
#define EXP2(x) __builtin_amdgcn_exp2f(x)
#else
#define EXP2(x) exp2f(x)
#endif
#define SCL 0.0450842200278f   /* (1/32) * log2(e) : scores kept in log2 domain */

__device__ __forceinline__ unsigned int pk2(float a, float b) {
    float2 f; f.x = a; f.y = b;
    union { __hip_bfloat162 h; unsigned int u; } c;
    c.h = __float22bfloat162_rn(f);
    return c.u;
}
__device__ __forceinline__ unsigned short f2bf(float f) {
    union { float f; unsigned int u; } v; v.f = f;
    unsigned int u = v.u;
    return (unsigned short)((u + 0x7FFFu + ((u >> 16) & 1u)) >> 16);  // RNE
}
__device__ __forceinline__ float blo(unsigned int u) {
    union { float f; unsigned int x; } v; v.x = u << 16; return v.f;
}
__device__ __forceinline__ float bhi(unsigned int u) {
    union { float f; unsigned int x; } v; v.x = u & 0xffff0000u; return v.f;
}

// ================= FUSED cooperative kernel: proj -> flash -> combine =================
__global__ __launch_bounds__(256, 2) void fused_all(const float* __restrict__ x,
                                                    const float* __restrict__ Wq,
                                                    unsigned short* __restrict__ q,
                                                    unsigned short* __restrict__ qT,
                                                    unsigned short* __restrict__ PO,
                                                    float* __restrict__ ML,
                                                    float* __restrict__ out) {
    cg::grid_group grid = cg::this_grid();
    __shared__ union {
        struct { float red[4 * 64 * 20]; } p;                                    // 20 KB
        struct { uint4 Qs4[512]; uint4 Ks4[512]; uint4 Vt4[512];
                 unsigned short Pb[4 * 16 * 72]; } f;                            // 33.75 KB
    } sm;
    const int G = gridDim.x;
    const int bid = blockIdx.x;
    const int t = threadIdx.x, lane = t & 63, w = t >> 6;
    const int m15 = lane & 15, q_ = lane >> 4;

    // ---------- Phase A: q = x @ Wq^T (split-K x4, LDS reduce) ----------
    for (int rb = bid; rb < 512; rb += G) {
        const int row0 = rb * 16;
        const float* xr = x + (size_t)(row0 + m15) * Dd + w * 256 + q_ * 8;
        const float* wr0 = Wq + (size_t)m15 * Dd + w * 256 + q_ * 8;
        f32x4 acc[4];
#pragma unroll
        for (int i = 0; i < 4; ++i) acc[i] = (f32x4){0.f, 0.f, 0.f, 0.f};
#pragma unroll
        for (int ks = 0; ks < 8; ++ks) {
            float4 a = *(const float4*)(xr + ks * 32);
            float4 b = *(const float4*)(xr + ks * 32 + 4);
            union { s16x8 v; uint4 u; } A;
            A.u.x = pk2(a.x, a.y); A.u.y = pk2(a.z, a.w);
            A.u.z = pk2(b.x, b.y); A.u.w = pk2(b.z, b.w);
#pragma unroll
            for (int ct = 0; ct < 4; ++ct) {
                const float* wr = wr0 + (size_t)ct * 16 * Dd + ks * 32;
                float4 wa = *(const float4*)wr;
                float4 wb = *(const float4*)(wr + 4);
                union { s16x8 v; uint4 u; } B;
                B.u.x = pk2(wa.x, wa.y); B.u.y = pk2(wa.z, wa.w);
                B.u.z = pk2(wb.x, wb.y); B.u.w = pk2(wb.z, wb.w);
                acc[ct] = __builtin_amdgcn_mfma_f32_16x16x32_bf16(A.v, B.v, acc[ct], 0, 0, 0);
            }
        }
#pragma unroll
        for (int ct = 0; ct < 4; ++ct)
            *(f32x4*)&sm.p.red[(w * 64 + ct * 16 + m15) * 20 + q_ * 4] = acc[ct];
        __syncthreads();
        const int col = t >> 2, r4 = (t & 3) * 4;
        f32x4 sum = *(const f32x4*)&sm.p.red[(0 * 64 + col) * 20 + r4];
#pragma unroll
        for (int v = 1; v < 4; ++v) sum += *(const f32x4*)&sm.p.red[(v * 64 + col) * 20 + r4];
        unsigned short u0 = f2bf(sum[0]), u1 = f2bf(sum[1]), u2 = f2bf(sum[2]), u3 = f2bf(sum[3]);
        q[(size_t)(row0 + r4 + 0) * Hh + col] = u0;
        q[(size_t)(row0 + r4 + 1) * Hh + col] = u1;
        q[(size_t)(row0 + r4 + 2) * Hh + col] = u2;
        q[(size_t)(row0 + r4 + 3) * Hh + col] = u3;
        ushort4 pkv; pkv.x = u0; pkv.y = u1; pkv.z = u2; pkv.w = u3;
        const int bb = row0 >> 11;
        *(ushort4*)&qT[((size_t)(bb * Hh + col)) * Ll + (row0 & 2047) + r4] = pkv;
        __syncthreads();
    }

    grid.sync();   // q/qT visible to all blocks

    // ---------- Phase B: split-KV flash (576 units) ----------
    for (int u = bid; u < 576; u += G) {
        const int b = u / 144;
        const int i = u % 144;
        int g = (int)((sqrtf(1.0f + 2.0f * (float)i) - 1.0f) * 0.5f);
        while (2 * g * (g + 1) > i) --g;
        while (2 * (g + 1) * (g + 2) <= i) ++g;
        const int r_ = i - 2 * g * (g + 1);
        const int qt = 4 * g + r_ / (g + 1);
        const int s  = r_ % (g + 1);
        const int ns = g + 1;
        const unsigned short* qb  = q  + (size_t)b * Ll * Hh;
        const unsigned short* qTb = qT + (size_t)b * Hh * Ll;

        __syncthreads();   // prior unit's readers of Qs4/Ks4/Vt4 are done
#pragma unroll
        for (int j = 0; j < 2; ++j) {   // stage Q tile
            int idx = t + j * 256;
            int r = idx >> 3, hc = idx & 7;
            sm.f.Qs4[hc * 64 + (r ^ hc)] =
                *(const uint4*)(qb + (size_t)(qt * 64 + r) * Hh + hc * 8);
        }
        f32x4 Oacc[4];
#pragma unroll
        for (int k = 0; k < 4; ++k) Oacc[k] = (f32x4){0.f, 0.f, 0.f, 0.f};
        float mr = -INFINITY, lr = 0.f;
        const int n_it = min(4, qt - 4 * s + 1);
        const int c_base = s * 256;
        const int row = qt * 64 + w * 16 + m15;
        unsigned short* Pr = sm.f.Pb + (w * 16 + m15) * 72;

        for (int it = 0; it < n_it; ++it) {
            const int c0 = c_base + it * 64;
            __syncthreads();
#pragma unroll
            for (int j = 0; j < 2; ++j) {   // K tile
                int idx = t + j * 256;
                int c = idx >> 3, hc = idx & 7;
                sm.f.Ks4[hc * 64 + (c ^ hc)] =
                    *(const uint4*)(qb + (size_t)(c0 + c) * Hh + hc * 8);
            }
#pragma unroll
            for (int j = 0; j < 2; ++j) {   // V^T tile
                int idx = t + j * 256;
                int h = idx >> 3, cc = idx & 7;
                sm.f.Vt4[cc * 64 + (h ^ cc)] =
                    *(const uint4*)(qTb + (size_t)h * Ll + c0 + cc * 8);
            }
            __syncthreads();
            f32x4 sc[4];
#pragma unroll
            for (int ct = 0; ct < 4; ++ct) sc[ct] = (f32x4){0.f, 0.f, 0.f, 0.f};
#pragma unroll
            for (int ks = 0; ks < 2; ++ks) {
                int hc = ks * 4 + q_;
                s16x8 Bq = *(const s16x8*)&sm.f.Qs4[hc * 64 + ((w * 16 + m15) ^ hc)];
#pragma unroll
                for (int ct = 0; ct < 4; ++ct) {
                    s16x8 Ak = *(const s16x8*)&sm.f.Ks4[hc * 64 + ((ct * 16 + m15) ^ hc)];
                    sc[ct] = __builtin_amdgcn_mfma_f32_16x16x32_bf16(Ak, Bq, sc[ct], 0, 0, 0);
                }
            }
            const bool diag = (4 * s + it) == qt;
            float v[16];
#pragma unroll
            for (int ct = 0; ct < 4; ++ct)
#pragma unroll
                for (int r = 0; r < 4; ++r) {
                    float sv = sc[ct][r] * SCL;
                    if (diag && (c0 + ct * 16 + q_ * 4 + r > row)) sv = -INFINITY;
                    v[ct * 4 + r] = sv;
                }
            float vmax = v[0];
#pragma unroll
            for (int k = 1; k < 16; ++k) vmax = fmaxf(vmax, v[k]);
            vmax = fmaxf(vmax, __shfl_xor(vmax, 16, 64));
            vmax = fmaxf(vmax, __shfl_xor(vmax, 32, 64));
            float mnew = fmaxf(mr, vmax);
            float alpha = EXP2(mr - mnew);
            float p[16];
            float psum = 0.f;
#pragma unroll
            for (int k = 0; k < 16; ++k) { p[k] = EXP2(v[k] - mnew); psum += p[k]; }
            psum += __shfl_xor(psum, 16, 64);
            psum += __shfl_xor(psum, 32, 64);
            lr = lr * alpha + psum;
            mr = mnew;
#pragma unroll
            for (int ht = 0; ht < 4; ++ht) Oacc[ht] *= alpha;
#pragma unroll
            for (int ct = 0; ct < 4; ++ct) {
                uint2 pr; pr.x = pk2(p[ct * 4 + 0], p[ct * 4 + 1]);
                pr.y = pk2(p[ct * 4 + 2], p[ct * 4 + 3]);
                *(uint2*)(Pr + ct * 16 + q_ * 4) = pr;
            }
#pragma unroll
            for (int kc = 0; kc < 2; ++kc) {
                int cc = kc * 4 + q_;
                s16x8 Bp = *(const s16x8*)(Pr + kc * 32 + q_ * 8);
#pragma unroll
                for (int ht = 0; ht < 4; ++ht) {
                    s16x8 Av = *(const s16x8*)&sm.f.Vt4[cc * 64 + ((ht * 16 + m15) ^ cc)];
                    Oacc[ht] = __builtin_amdgcn_mfma_f32_16x16x32_bf16(Av, Bp, Oacc[ht], 0, 0, 0);
                }
            }
        }
        if (ns == 1) {
            const float inv = 1.0f / lr;
#pragma unroll
            for (int ht = 0; ht < 4; ++ht)
                *(f32x4*)&out[(size_t)(b * Ll + qt * 64 + w * 16 + m15) * 64 + ht * 16 + q_ * 4]
                    = Oacc[ht] * inv;
        } else {
            const int bq = b * 32 + qt;
            const size_t base = ((size_t)(bq * 8 + s)) * 4096;
#pragma unroll
            for (int ht = 0; ht < 4; ++ht) {
                ushort4 pw;
                pw.x = f2bf(Oacc[ht][0]); pw.y = f2bf(Oacc[ht][1]);
                pw.z = f2bf(Oacc[ht][2]); pw.w = f2bf(Oacc[ht][3]);
                *(ushort4*)&PO[base + (size_t)(w * 16 + m15) * 64 + ht * 16 + q_ * 4] = pw;
            }
            if (q_ == 0) {
                float* mlp = ML + ((size_t)(bq * 8 + s)) * 128;
                mlp[(w * 16 + m15) * 2 + 0] = mr;
                mlp[(w * 16 + m15) * 2 + 1] = lr;
            }
        }
    }

    grid.sync();   // PO/ML visible

    // ---------- Phase C: combine (224 chunks: b x qt(4..31) x row-half) ----------
    for (int cb = bid; cb < 224; cb += G) {
        const int b = cb / 56;
        const int rem = cb % 56;
        const int qt = 4 + rem / 2;
        const int half = rem & 1;
        const int bq = b * 32 + qt;
        const int ns = (qt >> 2) + 1;
        const int r = half * 32 + (t >> 3);
        const int c8 = (t & 7) * 8;
        const float* mlp = ML + (size_t)bq * 1024;
        const unsigned short* pob = PO + (size_t)bq * 32768;
        float M = -INFINITY;
        for (int si = 0; si < ns; ++si) M = fmaxf(M, mlp[si * 128 + r * 2]);
        float L = 0.f;
        float a[8];
#pragma unroll
        for (int k = 0; k < 8; ++k) a[k] = 0.f;
        for (int si = 0; si < ns; ++si) {
            float ms = mlp[si * 128 + r * 2], ls = mlp[si * 128 + r * 2 + 1];
            float wgt = EXP2(ms - M);
            L += ls * wgt;
            uint4 pv = *(const uint4*)(pob + (size_t)si * 4096 + r * 64 + c8);
            a[0] += wgt * blo(pv.x); a[1] += wgt * bhi(pv.x);
            a[2] += wgt * blo(pv.y); a[3] += wgt * bhi(pv.y);
            a[4] += wgt * blo(pv.z); a[5] += wgt * bhi(pv.z);
            a[6] += wgt * blo(pv.w); a[7] += wgt * bhi(pv.w);
        }
        const float inv = 1.0f / L;
        float* op = out + (size_t)(b * Ll + qt * 64 + r) * 64 + c8;
        f32x4 o0 = {a[0] * inv, a[1] * inv, a[2] * inv, a[3] * inv};
        f32x4 o1 = {a[4] * inv, a[5] * inv, a[6] * inv, a[7] * inv};
        *(f32x4*)op = o0;
        *(f32x4*)(op + 4) = o1;
    }
}

// ================= Fallback path (R6 three-kernel, known good) =================
__global__ __launch_bounds__(256) void proj_mfma(const float* __restrict__ x,
                                                 const float* __restrict__ Wq,
                                                 unsigned short* __restrict__ q,
                                                 unsigned short* __restrict__ qT) {
    __shared__ float red[4 * 64 * 20];
    const int t = threadIdx.x;
    const int lane = t & 63;
    const int wv = t >> 6;
    const int m15 = lane & 15, q_ = lane >> 4;
    const int row0 = blockIdx.x * 16;
    const float* xr = x + (size_t)(row0 + m15) * Dd + wv * 256 + q_ * 8;
    const float* wr0 = Wq + (size_t)m15 * Dd + wv * 256 + q_ * 8;
    f32x4 acc[4];
#pragma unroll
    for (int i = 0; i < 4; ++i) acc[i] = (f32x4){0.f, 0.f, 0.f, 0.f};
#pragma unroll
    for (int ks = 0; ks < 8; ++ks) {
        float4 a = *(const float4*)(xr + ks * 32);
        float4 b = *(const float4*)(xr + ks * 32 + 4);
        union { s16x8 v; uint4 u; } A;
        A.u.x = pk2(a.x, a.y); A.u.y = pk2(a.z, a.w);
        A.u.z = pk2(b.x, b.y); A.u.w = pk2(b.z, b.w);
#pragma unroll
        for (int ct = 0; ct < 4; ++ct) {
            const float* wr = wr0 + (size_t)ct * 16 * Dd + ks * 32;
            float4 wa = *(const float4*)wr;
            float4 wb = *(const float4*)(wr + 4);
            union { s16x8 v; uint4 u; } B;
            B.u.x = pk2(wa.x, wa.y); B.u.y = pk2(wa.z, wa.w);
            B.u.z = pk2(wb.x, wb.y); B.u.w = pk2(wb.z, wb.w);
            acc[ct] = __builtin_amdgcn_mfma_f32_16x16x32_bf16(A.v, B.v, acc[ct], 0, 0, 0);
        }
    }
#pragma unroll
    for (int ct = 0; ct < 4; ++ct)
        *(f32x4*)&red[(wv * 64 + ct * 16 + m15) * 20 + q_ * 4] = acc[ct];
    __syncthreads();
    const int col = t >> 2, r4 = (t & 3) * 4;
    f32x4 sum = *(const f32x4*)&red[(0 * 64 + col) * 20 + r4];
#pragma unroll
    for (int v = 1; v < 4; ++v) sum += *(const f32x4*)&red[(v * 64 + col) * 20 + r4];
    unsigned short u0 = f2bf(sum[0]), u1 = f2bf(sum[1]), u2 = f2bf(sum[2]), u3 = f2bf(sum[3]);
    q[(size_t)(row0 + r4 + 0) * Hh + col] = u0;
    q[(size_t)(row0 + r4 + 1) * Hh + col] = u1;
    q[(size_t)(row0 + r4 + 2) * Hh + col] = u2;
    q[(size_t)(row0 + r4 + 3) * Hh + col] = u3;
    ushort4 pkv; pkv.x = u0; pkv.y = u1; pkv.z = u2; pkv.w = u3;
    const int b = row0 >> 11;
    *(ushort4*)&qT[((size_t)(b * Hh + col)) * Ll + (row0 & 2047) + r4] = pkv;
}

__global__ __launch_bounds__(256, 3) void flash_mfma(const unsigned short* __restrict__ qg,
                                                     const unsigned short* __restrict__ qTg,
                                                     float* __restrict__ PO,
                                                     float* __restrict__ ML,
                                                     float* __restrict__ out) {
    const int i = blockIdx.x;
    const int b = blockIdx.y;
    int g = (int)((sqrtf(1.0f + 2.0f * (float)i) - 1.0f) * 0.5f);
    while (2 * g * (g + 1) > i) --g;
    while (2 * (g + 1) * (g + 2) <= i) ++g;
    const int r_ = i - 2 * g * (g + 1);
    const int qt = 4 * g + r_ / (g + 1);
    const int s  = r_ % (g + 1);
    const int ns = g + 1;
    __shared__ uint4 Qs4[512], Ks4[512], Vt4[512];
    __shared__ __align__(16) unsigned short Pb[4 * 16 * 72];
    const int t = threadIdx.x, lane = t & 63, w = t >> 6;
    const int m15 = lane & 15, q_ = lane >> 4;
    const unsigned short* qb  = qg  + (size_t)b * Ll * Hh;
    const unsigned short* qTb = qTg + (size_t)b * Hh * Ll;
#pragma unroll
    for (int j = 0; j < 2; ++j) {
        int idx = t + j * 256;
        int r = idx >> 3, hc = idx & 7;
        Qs4[hc * 64 + (r ^ hc)] = *(const uint4*)(qb + (size_t)(qt * 64 + r) * Hh + hc * 8);
    }
    f32x4 Oacc[4];
#pragma unroll
    for (int k = 0; k < 4; ++k) Oacc[k] = (f32x4){0.f, 0.f, 0.f, 0.f};
    float mr = -INFINITY, lr = 0.f;
    const int n_it = min(4, qt - 4 * s + 1);
    const int c_base = s * 256;
    const int row = qt * 64 + w * 16 + m15;
    unsigned short* Pr = Pb + (w * 16 + m15) * 72;
    for (int it = 0; it < n_it; ++it) {
        const int c0 = c_base + it * 64;
        __syncthreads();
#pragma unroll
        for (int j = 0; j < 2; ++j) {
            int idx = t + j * 256;
            int c = idx >> 3, hc = idx & 7;
            Ks4[hc * 64 + (c ^ hc)] = *(const uint4*)(qb + (size_t)(c0 + c) * Hh + hc * 8);
        }
#pragma unroll
        for (int j = 0; j < 2; ++j) {
            int idx = t + j * 256;
            int h = idx >> 3, cc = idx & 7;
            Vt4[cc * 64 + (h ^ cc)] = *(const uint4*)(qTb + (size_t)h * Ll + c0 + cc * 8);
        }
        __syncthreads();
        f32x4 sc[4];
#pragma unroll
        for (int ct = 0; ct < 4; ++ct) sc[ct] = (f32x4){0.f, 0.f, 0.f, 0.f};
#pragma unroll
        for (int ks = 0; ks < 2; ++ks) {
            int hc = ks * 4 + q_;
            s16x8 Bq = *(const s16x8*)&Qs4[hc * 64 + ((w * 16 + m15) ^ hc)];
#pragma unroll
            for (int ct = 0; ct < 4; ++ct) {
                s16x8 Ak = *(const s16x8*)&Ks4[hc * 64 + ((ct * 16 + m15) ^ hc)];
                sc[ct] = __builtin_amdgcn_mfma_f32_16x16x32_bf16(Ak, Bq, sc[ct], 0, 0, 0);
            }
        }
        const bool diag = (4 * s + it) == qt;
        float v[16];
#pragma unroll
        for (int ct = 0; ct < 4; ++ct)
#pragma unroll
            for (int r = 0; r < 4; ++r) {
                float sv = sc[ct][r] * SCL;
                if (diag && (c0 + ct * 16 + q_ * 4 + r > row)) sv = -INFINITY;
                v[ct * 4 + r] = sv;
            }
        float vmax = v[0];
#pragma unroll
        for (int k = 1; k < 16; ++k) vmax = fmaxf(vmax, v[k]);
        vmax = fmaxf(vmax, __shfl_xor(vmax, 16, 64));
        vmax = fmaxf(vmax, __shfl_xor(vmax, 32, 64));
        float mnew = fmaxf(mr, vmax);
        float alpha = EXP2(mr - mnew);
        float p[16];
        float psum = 0.f;
#pragma unroll
        for (int k = 0; k < 16; ++k) { p[k] = EXP2(v[k] - mnew); psum += p[k]; }
        psum += __shfl_xor(psum, 16, 64);
        psum += __shfl_xor(psum, 32, 64);
        lr = lr * alpha + psum;
        mr = mnew;
#pragma unroll
        for (int ht = 0; ht < 4; ++ht) Oacc[ht] *= alpha;
#pragma unroll
        for (int ct = 0; ct < 4; ++ct) {
            uint2 pr; pr.x = pk2(p[ct * 4 + 0], p[ct * 4 + 1]);
            pr.y = pk2(p[ct * 4 + 2], p[ct * 4 + 3]);
            *(uint2*)(Pr + ct * 16 + q_ * 4) = pr;
        }
#pragma unroll
        for (int kc = 0; kc < 2; ++kc) {
            int cc = kc * 4 + q_;
            s16x8 Bp = *(const s16x8*)(Pr + kc * 32 + q_ * 8);
#pragma unroll
            for (int ht = 0; ht < 4; ++ht) {
                s16x8 Av = *(const s16x8*)&Vt4[cc * 64 + ((ht * 16 + m15) ^ cc)];
                Oacc[ht] = __builtin_amdgcn_mfma_f32_16x16x32_bf16(Av, Bp, Oacc[ht], 0, 0, 0);
            }
        }
    }
    if (ns == 1) {
        const float inv = 1.0f / lr;
#pragma unroll
        for (int ht = 0; ht < 4; ++ht)
            *(f32x4*)&out[(size_t)(b * Ll + qt * 64 + w * 16 + m15) * 64 + ht * 16 + q_ * 4]
                = Oacc[ht] * inv;
        return;
    }
    const int bq = b * 32 + qt;
    const size_t base = ((size_t)(bq * 8 + s)) * 4096;
#pragma unroll
    for (int ht = 0; ht < 4; ++ht)
        *(f32x4*)&PO[base + (size_t)(w * 16 + m15) * 64 + ht * 16 + q_ * 4] = Oacc[ht];
    if (q_ == 0) {
        float* mlp = ML + ((size_t)(bq * 8 + s)) * 128;
        mlp[(w * 16 + m15) * 2 + 0] = mr;
        mlp[(w * 16 + m15) * 2 + 1] = lr;
    }
}

__global__ __launch_bounds__(256) void combine_k(const float* __restrict__ PO,
                                                 const float* __restrict__ ML,
                                                 float* __restrict__ out) {
    const int b = blockIdx.x / 28;
    const int qt = blockIdx.x % 28 + 4;
    const int bq = b * 32 + qt;
    const int ns = (qt >> 2) + 1;
    const int t = threadIdx.x;
    const int r = blockIdx.y * 32 + (t >> 3);
    const int c8 = (t & 7) * 8;
    const float* mlp = ML + (size_t)bq * 8 * 128;
    const float* pob = PO + (size_t)bq * 8 * 4096;
    float M = -INFINITY;
    for (int si = 0; si < ns; ++si) M = fmaxf(M, mlp[si * 128 + r * 2]);
    float L = 0.f;
    f32x4 a0 = {0.f, 0.f, 0.f, 0.f}, a1 = a0;
    for (int si = 0; si < ns; ++si) {
        float ms = mlp[si * 128 + r * 2], ls = mlp[si * 128 + r * 2 + 1];
        float wgt = EXP2(ms - M);
        L += ls * wgt;
        const f32x4* sp = (const f32x4*)(pob + (size_t)si * 4096 + r * 64 + c8);
        a0 += wgt * sp[0];
        a1 += wgt * sp[1];
    }
    float inv = 1.0f / L;
    f32x4* op = (f32x4*)(out + (size_t)(b * Ll + qt * 64 + r) * 64 + c8);
    op[0] = a0 * inv;
    op[1] = a1 * inv;
}

extern "C" void kernel_launch(void* const* d_in, const int* in_sizes, int n_in,
                              void* d_out, int out_size, void* d_ws, size_t ws_size,
                              hipStream_t stream) {
    const float* x  = (const float*)d_in[0];   // [4,2048,1024]
    const float* Wq = (const float*)d_in[1];   // [64,1024]
    float* out = (float*)d_out;                // [4,2048,64] fp32
    char* ws = (char*)d_ws;
    unsigned short* q   = (unsigned short*)ws;                 // 1 MB   bf16 q
    unsigned short* qT  = (unsigned short*)(ws + (1 << 20));   // 1 MB   bf16 qT
    unsigned short* POb = (unsigned short*)(ws + (2 << 20));   // 8 MB   bf16 partials (fused)
    float* ML  = (float*)(ws + (10 << 20));                    // 512 KB (m,l)
    float* POf = (float*)(ws + (11 << 20));                    // 16 MB  fp32 partials (fallback)
    float* MLf = (float*)(ws + (27 << 20));                    // 512 KB (fallback)

    // Cooperative grid size: 2 blocks/CU target, clamped by reported occupancy.
    int nb = 0;
    hipError_t oe = hipOccupancyMaxActiveBlocksPerMultiprocessor(
        &nb, (const void*)fused_all, 256, 0);
    if (oe != hipSuccess) nb = 0;
    int G = nb * 256;
    if (G > 512) G = 512;

    bool launched = false;
    if (G >= 128) {
        void* args[] = {(void*)&x, (void*)&Wq, (void*)&q, (void*)&qT,
                        (void*)&POb, (void*)&ML, (void*)&out};
        hipError_t e = hipLaunchCooperativeKernel((const void*)fused_all,
                                                  dim3(G), dim3(256), args, 0, stream);
        launched = (e == hipSuccess);
    }
    if (!launched) {
        proj_mfma<<<512, 256, 0, stream>>>(x, Wq, q, qT);
        flash_mfma<<<dim3(144, Bb), 256, 0, stream>>>(q, qT, POf, MLf, out);
        combine_k<<<dim3(112, 2), 256, 0, stream>>>(POf, MLf, out);
    }
}

// Round 8
// 116.609 us; speedup vs baseline: 1.4805x; 1.4805x over previous
//
#include <hip/hip_runtime.h>
#include <hip/hip_bf16.h>
#include <cmath>

#define Bb 4
#define Ll 2048
#define Dd 1024
#define Hh 64

typedef float f32x4 __attribute__((ext_vector_type(4)));
typedef short s16x8 __attribute__((ext_vector_type(8)));

#if __has_builtin(__builtin_amdgcn_exp2f)
#define EXP2(x) __builtin_amdgcn_exp2f(x)
#else
#define EXP2(x) exp2f(x)
#endif
#define SCL 0.0450842200278f   /* (1/32) * log2(e) : scores kept in log2 domain */

__device__ __forceinline__ unsigned int pk2(float a, float b) {
    float2 f; f.x = a; f.y = b;
    union { __hip_bfloat162 h; unsigned int u; } c;
    c.h = __float22bfloat162_rn(f);
    return c.u;
}
__device__ __forceinline__ unsigned short f2bf(float f) {
    union { float f; unsigned int u; } v; v.f = f;
    unsigned int u = v.u;
    return (unsigned short)((u + 0x7FFFu + ((u >> 16) & 1u)) >> 16);  // RNE
}
__device__ __forceinline__ float blo(unsigned int u) {
    union { float f; unsigned int x; } v; v.x = u << 16; return v.f;
}
__device__ __forceinline__ float bhi(unsigned int u) {
    union { float f; unsigned int x; } v; v.x = u & 0xffff0000u; return v.f;
}

// ---------------- Kernel 1: q = x @ Wq^T, bf16 MFMA, SPLIT-K x4 (r6, known good) ----------------
__global__ __launch_bounds__(256) void proj_mfma(const float* __restrict__ x,
                                                 const float* __restrict__ Wq,
                                                 unsigned short* __restrict__ q,
                                                 unsigned short* __restrict__ qT) {
    __shared__ float red[4 * 64 * 20];             // [wv][col][row16 + pad4] = 20 KB
    const int t = threadIdx.x;
    const int lane = t & 63;
    const int wv = t >> 6;
    const int m15 = lane & 15, q_ = lane >> 4;
    const int row0 = blockIdx.x * 16;
    const float* xr = x + (size_t)(row0 + m15) * Dd + wv * 256 + q_ * 8;
    const float* wr0 = Wq + (size_t)m15 * Dd + wv * 256 + q_ * 8;

    f32x4 acc[4];
#pragma unroll
    for (int i = 0; i < 4; ++i) acc[i] = (f32x4){0.f, 0.f, 0.f, 0.f};
#pragma unroll
    for (int ks = 0; ks < 8; ++ks) {
        float4 a = *(const float4*)(xr + ks * 32);
        float4 b = *(const float4*)(xr + ks * 32 + 4);
        union { s16x8 v; uint4 u; } A;
        A.u.x = pk2(a.x, a.y); A.u.y = pk2(a.z, a.w);
        A.u.z = pk2(b.x, b.y); A.u.w = pk2(b.z, b.w);
#pragma unroll
        for (int ct = 0; ct < 4; ++ct) {
            const float* wr = wr0 + (size_t)ct * 16 * Dd + ks * 32;
            float4 wa = *(const float4*)wr;
            float4 wb = *(const float4*)(wr + 4);
            union { s16x8 v; uint4 u; } B;
            B.u.x = pk2(wa.x, wa.y); B.u.y = pk2(wa.z, wa.w);
            B.u.z = pk2(wb.x, wb.y); B.u.w = pk2(wb.z, wb.w);
            acc[ct] = __builtin_amdgcn_mfma_f32_16x16x32_bf16(A.v, B.v, acc[ct], 0, 0, 0);
        }
    }
#pragma unroll
    for (int ct = 0; ct < 4; ++ct)
        *(f32x4*)&red[(wv * 64 + ct * 16 + m15) * 20 + q_ * 4] = acc[ct];
    __syncthreads();
    const int col = t >> 2, r4 = (t & 3) * 4;
    f32x4 sum = *(const f32x4*)&red[(0 * 64 + col) * 20 + r4];
#pragma unroll
    for (int v = 1; v < 4; ++v) sum += *(const f32x4*)&red[(v * 64 + col) * 20 + r4];
    unsigned short u0 = f2bf(sum[0]), u1 = f2bf(sum[1]), u2 = f2bf(sum[2]), u3 = f2bf(sum[3]);
    q[(size_t)(row0 + r4 + 0) * Hh + col] = u0;
    q[(size_t)(row0 + r4 + 1) * Hh + col] = u1;
    q[(size_t)(row0 + r4 + 2) * Hh + col] = u2;
    q[(size_t)(row0 + r4 + 3) * Hh + col] = u3;
    ushort4 pkv; pkv.x = u0; pkv.y = u1; pkv.z = u2; pkv.w = u3;
    const int b = row0 >> 11;
    *(ushort4*)&qT[((size_t)(b * Hh + col)) * Ll + (row0 & 2047) + r4] = pkv;
}

// ---------------- Kernel 2: BARRIER-FREE wave-autonomous flash ----------------
// Unit = one WAVE: (b, qt16 [BM=16 q-rows], slice of <=4 BN=64 kv-tiles).
// All MFMA A/B frags load DIRECTLY from global q/qT (L2-hot, 16 B/lane) -> no LDS
// staging, zero __syncthreads. P transposes via wave-private LDS (same-wave RAW).
// 2304 units = 576 blocks x 4 waves. Lane(m15) owns q-row m15; q_ spans kv/h.
__global__ __launch_bounds__(256, 2) void flash_wave(const unsigned short* __restrict__ qg,
                                                     const unsigned short* __restrict__ qTg,
                                                     unsigned short* __restrict__ PO,
                                                     float* __restrict__ ML,
                                                     float* __restrict__ out) {
    __shared__ __align__(16) unsigned short Pb[4 * 16 * 72];  // per-wave P rows
    const int t = threadIdx.x, lane = t & 63, w = t >> 6;
    const int m15 = lane & 15, q_ = lane >> 4;
    const int u = blockIdx.x * 4 + w;               // 0..2303
    const int b = u / 576;
    const int i = u % 576;
    // decode i -> (g, qt16, s): group g has 4 qt16 values, each with ns=ceil((g+1)/4) slices
    int g = 0, base = 0;
    for (;;) {
        int sz = 4 * ((g + 4) >> 2);
        if (base + sz <= i) { base += sz; ++g; } else break;
    }
    const int nsg = (g + 4) >> 2;                   // slices per qt16 in this group
    const int r_ = i - base;
    const int qt16 = 4 * g + r_ / nsg;
    const int s = r_ % nsg;
    const int nt = g + 1;                           // kv-tiles for this qt16
    const int n_it = min(4, nt - 4 * s);

    const unsigned short* qb  = qg  + (size_t)b * Ll * Hh;
    const unsigned short* qTb = qTg + (size_t)b * Hh * Ll;
    const int row = qt16 * 16 + m15;                // this lane's q-row
    unsigned short* Pr = Pb + (w * 16 + m15) * 72;  // wave-private P row

    // persistent Q B-frags: B[n=m15][k=(ks*4+q_)*8 ..+7]
    s16x8 Bq0 = *(const s16x8*)(qb + (size_t)row * Hh + q_ * 8);
    s16x8 Bq1 = *(const s16x8*)(qb + (size_t)row * Hh + 32 + q_ * 8);

    f32x4 Oacc[4];
#pragma unroll
    for (int k = 0; k < 4; ++k) Oacc[k] = (f32x4){0.f, 0.f, 0.f, 0.f};
    float mr = -INFINITY, lr = 0.f;

    for (int it = 0; it < n_it; ++it) {
        const int j = 4 * s + it;
        const int c0 = j * 64;
        // S^T = K.Q^T : A(K)[m=kv c0+ct*16+m15][k] straight from global
        const unsigned short* kb = qb + (size_t)(c0 + m15) * Hh + q_ * 8;
        f32x4 sc[4];
#pragma unroll
        for (int ct = 0; ct < 4; ++ct) sc[ct] = (f32x4){0.f, 0.f, 0.f, 0.f};
#pragma unroll
        for (int ks = 0; ks < 2; ++ks) {
            const s16x8 Bq = ks ? Bq1 : Bq0;
#pragma unroll
            for (int ct = 0; ct < 4; ++ct) {
                s16x8 Ak = *(const s16x8*)(kb + ct * 16 * Hh + ks * 32);
                sc[ct] = __builtin_amdgcn_mfma_f32_16x16x32_bf16(Ak, Bq, sc[ct], 0, 0, 0);
            }
        }
        const bool diag = (j == g);
        float v[16];
#pragma unroll
        for (int ct = 0; ct < 4; ++ct)
#pragma unroll
            for (int r = 0; r < 4; ++r) {
                float sv = sc[ct][r] * SCL;        // log2-domain score
                if (diag && (c0 + ct * 16 + q_ * 4 + r > row)) sv = -INFINITY;
                v[ct * 4 + r] = sv;
            }
        float vmax = v[0];
#pragma unroll
        for (int k = 1; k < 16; ++k) vmax = fmaxf(vmax, v[k]);
        vmax = fmaxf(vmax, __shfl_xor(vmax, 16, 64));
        vmax = fmaxf(vmax, __shfl_xor(vmax, 32, 64));
        float mnew = fmaxf(mr, vmax);
        float alpha = EXP2(mr - mnew);             // first iter: exp2(-inf)=0
        float p[16];
        float psum = 0.f;
#pragma unroll
        for (int k = 0; k < 16; ++k) { p[k] = EXP2(v[k] - mnew); psum += p[k]; }
        psum += __shfl_xor(psum, 16, 64);
        psum += __shfl_xor(psum, 32, 64);
        lr = lr * alpha + psum;
        mr = mnew;
#pragma unroll
        for (int ht = 0; ht < 4; ++ht) Oacc[ht] *= alpha;
#pragma unroll
        for (int ct = 0; ct < 4; ++ct) {           // P row -> LDS (same-wave RAW)
            uint2 pr; pr.x = pk2(p[ct * 4 + 0], p[ct * 4 + 1]);
            pr.y = pk2(p[ct * 4 + 2], p[ct * 4 + 3]);
            *(uint2*)(Pr + ct * 16 + q_ * 4) = pr;
        }
        // O^T += V^T.P : A(V^T)[m=h ht*16+m15][k=kv cc*8] straight from qT
        const unsigned short* vb = qTb + (size_t)m15 * Ll + c0 + q_ * 8;
#pragma unroll
        for (int kc = 0; kc < 2; ++kc) {
            s16x8 Bp = *(const s16x8*)(Pr + kc * 32 + q_ * 8);
#pragma unroll
            for (int ht = 0; ht < 4; ++ht) {
                s16x8 Av = *(const s16x8*)(vb + (size_t)ht * 16 * Ll + kc * 32);
                Oacc[ht] = __builtin_amdgcn_mfma_f32_16x16x32_bf16(Av, Bp, Oacc[ht], 0, 0, 0);
            }
        }
    }

    if (nsg == 1) {
        // whole row in this wave: normalize, write out directly
        const float inv = 1.0f / lr;
#pragma unroll
        for (int ht = 0; ht < 4; ++ht)
            *(f32x4*)&out[(size_t)(b * Ll + row) * Hh + ht * 16 + q_ * 4] = Oacc[ht] * inv;
        return;
    }
    // publish bf16 partial + (m,l)
    const size_t pbase = ((size_t)((b * 128 + qt16) * 8 + s)) * 1024;
#pragma unroll
    for (int ht = 0; ht < 4; ++ht) {
        ushort4 pw;
        pw.x = f2bf(Oacc[ht][0]); pw.y = f2bf(Oacc[ht][1]);
        pw.z = f2bf(Oacc[ht][2]); pw.w = f2bf(Oacc[ht][3]);
        *(ushort4*)&PO[pbase + (size_t)m15 * 64 + ht * 16 + q_ * 4] = pw;
    }
    if (q_ == 0) {
        float* mlp = ML + ((size_t)((b * 128 + qt16) * 8 + s)) * 32;
        mlp[m15 * 2 + 0] = mr;
        mlp[m15 * 2 + 1] = lr;
    }
}

// ---------------- Kernel 3: combine slices (qt16 >= 16 only; log2 domain) ----------------
// grid 448 = 4 b x 112 qt16. Thread: row = t>>4, cols (t&15)*4..+3.
__global__ __launch_bounds__(256) void combine_k(const unsigned short* __restrict__ PO,
                                                 const float* __restrict__ ML,
                                                 float* __restrict__ out) {
    const int b = blockIdx.x / 112;
    const int qt16 = 16 + blockIdx.x % 112;
    const int ns = ((qt16 >> 2) + 4) >> 2;         // ceil((qt16/4+1)/4), 2..8
    const int t = threadIdx.x;
    const int r = t >> 4;
    const int c4 = (t & 15) * 4;
    const float* mlp = ML + ((size_t)(b * 128 + qt16) * 8) * 32;
    const unsigned short* pob = PO + ((size_t)(b * 128 + qt16) * 8) * 1024;
    float M = -INFINITY;
    for (int si = 0; si < ns; ++si) M = fmaxf(M, mlp[si * 32 + r * 2]);
    float L = 0.f;
    float a0 = 0.f, a1 = 0.f, a2 = 0.f, a3 = 0.f;
    for (int si = 0; si < ns; ++si) {
        float ms = mlp[si * 32 + r * 2], ls = mlp[si * 32 + r * 2 + 1];
        float wgt = EXP2(ms - M);
        L += ls * wgt;
        uint2 pv = *(const uint2*)(pob + (size_t)si * 1024 + r * 64 + c4);
        a0 += wgt * blo(pv.x); a1 += wgt * bhi(pv.x);
        a2 += wgt * blo(pv.y); a3 += wgt * bhi(pv.y);
    }
    const float inv = 1.0f / L;
    f32x4 o; o[0] = a0 * inv; o[1] = a1 * inv; o[2] = a2 * inv; o[3] = a3 * inv;
    *(f32x4*)&out[(size_t)(b * Ll + qt16 * 16 + r) * Hh + c4] = o;
}

extern "C" void kernel_launch(void* const* d_in, const int* in_sizes, int n_in,
                              void* d_out, int out_size, void* d_ws, size_t ws_size,
                              hipStream_t stream) {
    const float* x  = (const float*)d_in[0];   // [4,2048,1024]
    const float* Wq = (const float*)d_in[1];   // [64,1024]
    float* out = (float*)d_out;                // [4,2048,64] fp32
    char* ws = (char*)d_ws;
    unsigned short* q  = (unsigned short*)ws;                 // 1 MB   bf16 q [B*L][64]
    unsigned short* qT = (unsigned short*)(ws + (1 << 20));   // 1 MB   bf16 qT [B][64][L]
    unsigned short* PO = (unsigned short*)(ws + (2 << 20));   // 8 MB   bf16 partials
    float* ML = (float*)(ws + (10 << 20));                    // 512 KB (m,l)

    proj_mfma<<<512, 256, 0, stream>>>(x, Wq, q, qT);
    flash_wave<<<576, 256, 0, stream>>>(q, qT, PO, ML, out);
    combine_k<<<448, 256, 0, stream>>>(PO, ML, out);
}